// Round 11
// baseline (91.290 us; speedup 1.0000x reference)
//
#include <hip/hip_runtime.h>

// MultiHeadAttention_3753801417043 — MI355X/gfx950
// B=32, S=512, D_IN=128, N_HEAD=8, DIM_MODEL=512, SCALE=8.
//   W_eff[k][n] = sum_h W[h*128+k][n]  (concat([x]*8)@W == x@W_eff)
//   Q/K/V = x @ W_eff + b     3-pass split-bf16 MFMA, bf16-hi output
//   fused attention v8:       v7 wave-private barrier-free loops, LDS cut to 66KB
//                             (4KB chunk slices, 16 steps) -> 2 blocks/CU, 16 waves:
//                             TLP, not intra-wave scheduling, hides the latency.

typedef unsigned short u16;
typedef __attribute__((ext_vector_type(8))) short bf16x8;
typedef __attribute__((ext_vector_type(4))) float f32x4;
typedef __attribute__((ext_vector_type(2))) float f32x2;
typedef __attribute__((ext_vector_type(2))) unsigned int u32x2;

__device__ inline u16 f2bf(float f) {            // round-to-nearest-even fp32->bf16
  unsigned u = __float_as_uint(f);
  u = u + 0x7fffu + ((u >> 16) & 1u);
  return (u16)(u >> 16);
}
__device__ inline float bf2f(u16 h) { return __uint_as_float(((unsigned)h) << 16); }

// async global->LDS, 16B per lane (wave-uniform LDS base + lane*16; linear layout)
__device__ inline void gl16(const u16* g, u16* l) {
  __builtin_amdgcn_global_load_lds(
      (const __attribute__((address_space(1))) unsigned int*)g,
      (__attribute__((address_space(3))) unsigned int*)l, 16, 0, 0);
}

#define VM0  asm volatile("s_waitcnt vmcnt(0)" ::: "memory")
#define LK0  asm volatile("s_waitcnt lgkmcnt(0)" ::: "memory")
#define SB0  __builtin_amdgcn_sched_barrier(0)

// ---- merged prep: blocks 0..95 = W_eff transpose+split; 96.. = x hi/lo split ----
__global__ __launch_bounds__(256)
void prep_all(const float* __restrict__ x,
              const float* __restrict__ Wq, const float* __restrict__ Wk,
              const float* __restrict__ Wv,
              u16* __restrict__ WTh, u16* __restrict__ WTl,
              u16* __restrict__ xh, u16* __restrict__ xl) {
  if (blockIdx.x < 96) {
    __shared__ float sm[128][17];
    int t  = blockIdx.x >> 5;
    int nb = blockIdx.x & 31;
    const float* W = (t == 0) ? Wq : (t == 1) ? Wk : Wv;
    int n0 = nb << 4;
    int nl = threadIdx.x & 15;
    int kq = threadIdx.x >> 4;
    float s[8];
#pragma unroll
    for (int i = 0; i < 8; ++i) s[i] = 0.f;
#pragma unroll
    for (int h = 0; h < 8; ++h)
#pragma unroll
      for (int i = 0; i < 8; ++i)
        s[i] += W[(h * 128 + kq + (i << 4)) * 512 + n0 + nl];
#pragma unroll
    for (int i = 0; i < 8; ++i) sm[kq + (i << 4)][nl] = s[i];
    __syncthreads();
    int no = threadIdx.x >> 4;
    int k8 = (threadIdx.x & 15) << 3;
    bf16x8 h8, l8;
#pragma unroll
    for (int c = 0; c < 8; ++c) {
      float v = sm[k8 + c][no];
      u16 h = f2bf(v);
      h8[c] = (short)h;
      l8[c] = (short)f2bf(v - bf2f(h));
    }
    long o = (long)t * 65536 + (long)(n0 + no) * 128 + k8;
    *(bf16x8*)&WTh[o] = h8;
    *(bf16x8*)&WTl[o] = l8;
  } else {
    int i = (blockIdx.x - 96) * 256 + threadIdx.x;
    const f32x4* xx = (const f32x4*)x;
    f32x4 a = xx[i * 2], b = xx[i * 2 + 1];
    float v[8] = {a[0], a[1], a[2], a[3], b[0], b[1], b[2], b[3]};
    bf16x8 h8, l8;
#pragma unroll
    for (int j = 0; j < 8; ++j) {
      u16 h = f2bf(v[j]);
      h8[j] = (short)h;
      l8[j] = (short)f2bf(v[j] - bf2f(h));
    }
    ((bf16x8*)xh)[i] = h8;
    ((bf16x8*)xl)[i] = l8;
  }
}

// ---- fused Q/K/V projection: 3-pass split-bf16, coalesced bf16 epilogue ----
__global__ __launch_bounds__(256, 2)
void proj_fused(const u16* __restrict__ xh, const u16* __restrict__ xl,
                const u16* __restrict__ WTh, const u16* __restrict__ WTl,
                u16* __restrict__ Qh, u16* __restrict__ Kh, u16* __restrict__ Vh,
                const float* __restrict__ bq, const float* __restrict__ bk,
                const float* __restrict__ bv) {
  __shared__ __align__(16) char ldsraw[65536];
  u16* st = (u16*)ldsraw;

  int tid = threadIdx.x;
  int bid = blockIdx.x;
  bid = (bid & 7) * 192 + (bid >> 3);          // XCD swizzle (1536 = 8×192)
  int which = bid % 3;
  int tile  = bid / 3;
  int mt = tile >> 2;
  int nt = tile & 3;

  const u16* Ah = xh + (long)mt * (128 * 128);
  const u16* Al = xl + (long)mt * (128 * 128);
  const u16* Bh = WTh + which * 65536 + nt * 16384;
  const u16* Bl = WTl + which * 65536 + nt * 16384;
  const float* bias = (which == 0) ? bq : (which == 1) ? bk : bv;
  u16* C = (which == 0) ? Qh : (which == 1) ? Kh : Vh;

  int lane = tid & 63;
  int wv = tid >> 6;
  int wm = (wv >> 1) << 6;
  int wn = (wv & 1) << 6;
  int frow = lane & 15;
  int fk = (lane >> 4) << 3;

  f32x4 acc[4][4];
#pragma unroll
  for (int i = 0; i < 4; ++i)
#pragma unroll
    for (int j = 0; j < 4; ++j) {
      f32x4 z = {0.f, 0.f, 0.f, 0.f};
      acc[i][j] = z;
    }

  for (int kk = 0; kk < 2; ++kk) {
    int k0 = kk << 6;
#pragma unroll
    for (int j = 0; j < 4; ++j) {
      int c = j * 256 + tid;
      int row = c >> 3;
      int scol = ((c & 7) ^ (row & 7)) << 3;
      int ga = row * 128 + k0 + scol;
      int lo = c << 3;
      gl16(Ah + ga, st + lo);
      gl16(Al + ga, st + 8192 + lo);
      gl16(Bh + ga, st + 16384 + lo);
      gl16(Bl + ga, st + 24576 + lo);
    }
    __syncthreads();
#pragma unroll
    for (int ks = 0; ks < 2; ++ks) {
      int kb = (ks << 5) + fk;
      bf16x8 a_h[4], a_l[4], b_h[4], b_l[4];
#pragma unroll
      for (int i = 0; i < 4; ++i) {
        int ar = wm + (i << 4) + frow;
        int ao = ar * 64 + (kb ^ ((ar & 7) << 3));
        a_h[i] = *(const bf16x8*)&st[ao];
        a_l[i] = *(const bf16x8*)&st[8192 + ao];
        int br = wn + (i << 4) + frow;
        int bo = br * 64 + (kb ^ ((br & 7) << 3));
        b_h[i] = *(const bf16x8*)&st[16384 + bo];
        b_l[i] = *(const bf16x8*)&st[24576 + bo];
      }
#pragma unroll
      for (int i = 0; i < 4; ++i)
#pragma unroll
        for (int j = 0; j < 4; ++j) {
          acc[i][j] = __builtin_amdgcn_mfma_f32_16x16x32_bf16(a_h[i], b_h[j], acc[i][j], 0, 0, 0);
          acc[i][j] = __builtin_amdgcn_mfma_f32_16x16x32_bf16(a_l[i], b_h[j], acc[i][j], 0, 0, 0);
          acc[i][j] = __builtin_amdgcn_mfma_f32_16x16x32_bf16(a_h[i], b_l[j], acc[i][j], 0, 0, 0);
        }
    }
    __syncthreads();
  }

  // Coalesced epilogue via per-wave fp32 LDS transpose (intra-wave, no barrier)
  float* tr = ((float*)ldsraw) + wv * 2112;
  int lr = lane >> 3;
  int c8 = (lane & 7) << 3;
  int colbase = (nt << 7) + wn + c8;
  float bb[8];
#pragma unroll
  for (int c = 0; c < 8; ++c) bb[c] = bias[colbase + c];
  long rowg0 = (long)(mt << 7) + wm;
#pragma unroll
  for (int q = 0; q < 2; ++q) {
#pragma unroll
    for (int il = 0; il < 2; ++il) {
      int i = (q << 1) + il;
#pragma unroll
      for (int j = 0; j < 4; ++j)
#pragma unroll
        for (int r = 0; r < 4; ++r)
          tr[((il << 4) + ((lane >> 4) << 2) + r) * 66 + (j << 4) + (lane & 15)] =
              acc[i][j][r];
    }
#pragma unroll
    for (int p = 0; p < 4; ++p) {
      int rr = (p << 3) + lr;
      float v[8];
      *(f32x2*)&v[0] = *(const f32x2*)&tr[rr * 66 + c8];
      *(f32x2*)&v[2] = *(const f32x2*)&tr[rr * 66 + c8 + 2];
      *(f32x2*)&v[4] = *(const f32x2*)&tr[rr * 66 + c8 + 4];
      *(f32x2*)&v[6] = *(const f32x2*)&tr[rr * 66 + c8 + 6];
      bf16x8 o8;
#pragma unroll
      for (int c = 0; c < 8; ++c) o8[c] = (short)f2bf(v[c] + bb[c]);
      *(bf16x8*)&C[(rowg0 + (q << 5) + rr) * 512 + colbase] = o8;
    }
  }
}

// ---- fused attention v8 ----
// 512 blocks (32 batches × 16 jb of 32 q-rows), 512 threads, 2 blocks/CU (66KB).
// Wave nw owns attn-cols/v-rows [nw*64,+64). Private 4KB slice [64 tok][32 feat]
// (64B rows, slot^((tok>>1)&3) swizzle), 16 steps/phase, barrier-free k-loops:
// {VM0(own); ds_read frags; lgkm0+SB0; stage next; MFMA}.
// LDS: QP[0,32K) Q [32q][512f] (ph1) aliased by P [32q][512] bf16 (ph2);
// B[32K,64K) 8 × 4KB wave slices; smax/ssum at 64K.
__global__ __launch_bounds__(512, 4)
void attn_fused(const u16* __restrict__ Q, const u16* __restrict__ K,
                const u16* __restrict__ V, float* __restrict__ OUT) {
  __shared__ __align__(16) char LDS[67584];
  u16* QP = (u16*)LDS;                   // 32KB Q (ph1) / P (ph2)
  u16* B  = (u16*)(LDS + 32768);         // 32KB: 8 wave-private 4KB slices
  float* smax = (float*)(LDS + 65536);   // [32][8]
  float* ssum = (float*)(LDS + 66560);   // [32][8]

  int tid = threadIdx.x;
  int p = blockIdx.x;
  int xcd = p & 7, idx = p >> 3;
  int b  = (xcd << 2) + (idx >> 4);      // 4 batches per XCD
  int jb = idx & 15;

  const u16* Qp = Q + ((long)b * 512 + jb * 32) * 512;
  const u16* Kp = K + (long)b * 262144;
  const u16* Vp = V + (long)b * 262144;

  int lane = tid & 63, nw = tid >> 6;
  int frow = lane & 15, hi4 = lane >> 4;
  u16* myB = B + (nw << 11);             // 2048 u16 = 4KB private slice
  int tokbase = nw << 6;                 // wave's 64 tokens / v-rows

  // wave-private stage: [64 tok][32 feat] at feat k0 (4 gl16, 16 toks × 64B each)
  auto stageW = [&](const u16* src, int k0) {
#pragma unroll
    for (int j = 0; j < 4; ++j) {
      int u = (j << 6) + lane;
      int tok = u >> 2, slot = u & 3;
      gl16(src + (long)(tokbase + tok) * 512 + k0 + ((slot ^ ((tok >> 1) & 3)) << 3),
           myB + (u << 3));
    }
  };
  auto rW = [&](int r) -> bf16x8 {       // private slice, row 0..63, this step's k
    return *(const bf16x8*)&myB[(r << 5) + ((hi4 ^ ((r >> 1) & 3)) << 3)];
  };
  auto rQ = [&](int row, int sl) -> bf16x8 {     // Q row 0..31, slot 0..63
    return *(const bf16x8*)&QP[(row << 9) + ((sl ^ (row & 7)) << 3)];
  };
  auto rP = [&](int row, int sl) -> bf16x8 {     // P row 0..31, 16B-slot 0..63 of 1KB row
    return *(const bf16x8*)(LDS + (((row << 10) + (sl << 4)) ^ ((row & 7) << 4)));
  };

  // prologue: stage Q (shared) + own K step-0; one full drain
#pragma unroll
  for (int j = 0; j < 4; ++j) {
    int u = (j << 9) + tid;
    int row = u >> 6, sl = u & 63;
    gl16(Qp + (long)row * 512 + ((sl ^ (row & 7)) << 3), QP + (u << 3));
  }
  stageW(Kp, 0);
  __syncthreads();                       // drains vmcnt; Q + K0 visible

  // ---------------- phase 1: S^T = K·Q^T, barrier-free ----------------
  f32x4 acc[4][2];
#pragma unroll
  for (int jj = 0; jj < 4; ++jj)
#pragma unroll
    for (int ii = 0; ii < 2; ++ii) {
      f32x4 z = {0.f, 0.f, 0.f, 0.f};
      acc[jj][ii] = z;
    }

  for (int s = 0; s < 16; ++s) {
    if (s) VM0;                          // own 4 stage loads complete
    bf16x8 qf[2], af[4];
#pragma unroll
    for (int ii = 0; ii < 2; ++ii)
      qf[ii] = rQ((ii << 4) + frow, (s << 2) + hi4);
#pragma unroll
    for (int jj = 0; jj < 4; ++jj)
      af[jj] = rW((jj << 4) + frow);
    LK0; SB0;                            // frag reads done; slice reusable
    if (s < 15) stageW(Kp, (s + 1) << 5);
    else        stageW(Vp, 0);           // prefetch own V step-0 under softmax
    __builtin_amdgcn_s_setprio(1);
#pragma unroll
    for (int jj = 0; jj < 4; ++jj)
#pragma unroll
      for (int ii = 0; ii < 2; ++ii)
        acc[jj][ii] = __builtin_amdgcn_mfma_f32_16x16x32_bf16(
            af[jj], qf[ii], acc[jj][ii], 0, 0, 0);
    __builtin_amdgcn_s_setprio(0);
  }

  // ---------------- softmax per q-row over 512 attn-cols ----------------
  float mx[2], sm[2], inv_[2];
#pragma unroll
  for (int ii = 0; ii < 2; ++ii) {
    float m = acc[0][ii][0];
#pragma unroll
    for (int jj = 0; jj < 4; ++jj)
#pragma unroll
      for (int r = 0; r < 4; ++r) m = fmaxf(m, acc[jj][ii][r]);
    m = fmaxf(m, __shfl_xor(m, 16));
    m = fmaxf(m, __shfl_xor(m, 32));
    mx[ii] = m;
  }
  if (hi4 == 0) {
#pragma unroll
    for (int ii = 0; ii < 2; ++ii) smax[(((ii << 4) + frow) << 3) + nw] = mx[ii];
  }
  __syncthreads();
#pragma unroll
  for (int ii = 0; ii < 2; ++ii) {
    f32x4 a = *(const f32x4*)&smax[((ii << 4) + frow) << 3];
    f32x4 c = *(const f32x4*)&smax[((((ii << 4) + frow) << 3) + 4)];
    mx[ii] = fmaxf(fmaxf(fmaxf(a[0], a[1]), fmaxf(a[2], a[3])),
                   fmaxf(fmaxf(c[0], c[1]), fmaxf(c[2], c[3])));
    sm[ii] = 0.f;
  }
#pragma unroll
  for (int jj = 0; jj < 4; ++jj)
#pragma unroll
    for (int ii = 0; ii < 2; ++ii)
#pragma unroll
      for (int r = 0; r < 4; ++r) {
        float pv = __expf((acc[jj][ii][r] - mx[ii]) * 0.125f);   // fold /8 scale
        acc[jj][ii][r] = pv;
        sm[ii] += pv;
      }
#pragma unroll
  for (int ii = 0; ii < 2; ++ii) {
    sm[ii] += __shfl_xor(sm[ii], 16);
    sm[ii] += __shfl_xor(sm[ii], 32);
  }
  if (hi4 == 0) {
#pragma unroll
    for (int ii = 0; ii < 2; ++ii) ssum[(((ii << 4) + frow) << 3) + nw] = sm[ii];
  }
  __syncthreads();
#pragma unroll
  for (int ii = 0; ii < 2; ++ii) {
    f32x4 a = *(const f32x4*)&ssum[((ii << 4) + frow) << 3];
    f32x4 c = *(const f32x4*)&ssum[((((ii << 4) + frow) << 3) + 4)];
    inv_[ii] = 1.f / (a[0] + a[1] + a[2] + a[3] + c[0] + c[1] + c[2] + c[3]);
  }
  // write P [32 q][512] over the Q region (all waves' Q reads finished before
  // the smax barrier), byte XOR ((qr&7)<<4), packed 8B per (jj,ii)
#pragma unroll
  for (int ii = 0; ii < 2; ++ii) {
    int qr = (ii << 4) + frow;
    int rowoff = qr << 10;
    int swz = (qr & 7) << 4;
#pragma unroll
    for (int jj = 0; jj < 4; ++jj) {
      int c0 = ((nw << 6) + (jj << 4) + (hi4 << 2)) << 1;
      unsigned lo = (unsigned)f2bf(acc[jj][ii][0] * inv_[ii]) |
                    ((unsigned)f2bf(acc[jj][ii][1] * inv_[ii]) << 16);
      unsigned hi = (unsigned)f2bf(acc[jj][ii][2] * inv_[ii]) |
                    ((unsigned)f2bf(acc[jj][ii][3] * inv_[ii]) << 16);
      u32x2 w = {lo, hi};
      *(u32x2*)(LDS + ((rowoff + c0) ^ swz)) = w;
    }
  }
  __syncthreads();                       // P visible; own V step-0 staged (drained)

  // ---------------- phase 2: OUT = V·P^T, barrier-free ----------------
  f32x4 o[4][2];
#pragma unroll
  for (int jj = 0; jj < 4; ++jj)
#pragma unroll
    for (int ii = 0; ii < 2; ++ii) {
      f32x4 z = {0.f, 0.f, 0.f, 0.f};
      o[jj][ii] = z;
    }

  for (int s = 0; s < 16; ++s) {
    if (s) VM0;
    bf16x8 pf[2], vf[4];
#pragma unroll
    for (int ii = 0; ii < 2; ++ii)
      pf[ii] = rP((ii << 4) + frow, (s << 2) + hi4);
#pragma unroll
    for (int jj = 0; jj < 4; ++jj)
      vf[jj] = rW((jj << 4) + frow);
    LK0; SB0;
    if (s < 15) stageW(Vp, (s + 1) << 5);
    __builtin_amdgcn_s_setprio(1);
#pragma unroll
    for (int jj = 0; jj < 4; ++jj)
#pragma unroll
      for (int ii = 0; ii < 2; ++ii)
        o[jj][ii] = __builtin_amdgcn_mfma_f32_16x16x32_bf16(
            vf[jj], pf[ii], o[jj][ii], 0, 0, 0);
    __builtin_amdgcn_s_setprio(0);
  }

  // epilogue: OUT[b, vrow, jb*32 + qcol]
  float* Ob = OUT + (long)b * 262144 + jb * 32;
#pragma unroll
  for (int jj = 0; jj < 4; ++jj)
#pragma unroll
    for (int ii = 0; ii < 2; ++ii)
#pragma unroll
      for (int r = 0; r < 4; ++r) {
        int vrow = (nw << 6) + (jj << 4) + (hi4 << 2) + r;
        int qc = (ii << 4) + frow;
        Ob[(long)vrow * 512 + qc] = o[jj][ii][r];
      }
}

extern "C" void kernel_launch(void* const* d_in, const int* in_sizes, int n_in,
                              void* d_out, int out_size, void* d_ws, size_t ws_size,
                              hipStream_t stream) {
  const float* x  = (const float*)d_in[0];
  const float* Wq = (const float*)d_in[1];
  const float* bq = (const float*)d_in[2];
  const float* Wk = (const float*)d_in[3];
  const float* bk = (const float*)d_in[4];
  const float* Wv = (const float*)d_in[5];
  const float* bv = (const float*)d_in[6];
  float* out = (float*)d_out;

  char* ws = (char*)d_ws;
  size_t off = 0;
  auto alloc = [&](size_t bytes) -> char* {
    char* p = ws + off;
    off = (off + bytes + 255) & ~(size_t)255;
    return p;
  };
  u16* WTh = (u16*)alloc((size_t)3 * 512 * 128 * 2);
  u16* WTl = (u16*)alloc((size_t)3 * 512 * 128 * 2);
  u16* xh  = (u16*)alloc((size_t)16384 * 128 * 2);
  u16* xl  = (u16*)alloc((size_t)16384 * 128 * 2);
  u16* Qh  = (u16*)alloc((size_t)16384 * 512 * 2);
  u16* Kh  = (u16*)alloc((size_t)16384 * 512 * 2);
  u16* Vh  = (u16*)alloc((size_t)16384 * 512 * 2);

  prep_all<<<1120, 256, 0, stream>>>(x, Wq, Wk, Wv, WTh, WTl, xh, xl);
  proj_fused<<<1536, 256, 0, stream>>>(xh, xl, WTh, WTl, Qh, Kh, Vh, bq, bk, bv);
  attn_fused<<<512, 512, 0, stream>>>(Qh, Kh, Vh, out);
}

// Round 12
// 82.940 us; speedup vs baseline: 1.1007x; 1.1007x over previous
//
#include <hip/hip_runtime.h>

// MultiHeadAttention_3753801417043 — MI355X/gfx950
// B=32, S=512, D_IN=128, N_HEAD=8, DIM_MODEL=512, SCALE=8.
//   W_eff[k][n] = sum_h W[h*128+k][n]  (concat([x]*8)@W == x@W_eff)
//   Q/K/V = x @ W_eff + b     3-pass split-bf16 MFMA, bf16-hi output
//   fused attention v9:       q=64/block (halves K/V staging), 32x32x16 MFMA
//                             (4x FLOP per staged byte vs v8), wave-private
//                             barrier-free k-loops, Q/P 64KB aliased in LDS.

typedef unsigned short u16;
typedef __attribute__((ext_vector_type(8))) short bf16x8;
typedef __attribute__((ext_vector_type(16))) float f32x16;
typedef __attribute__((ext_vector_type(4))) float f32x4;
typedef __attribute__((ext_vector_type(2))) float f32x2;
typedef __attribute__((ext_vector_type(2))) unsigned int u32x2;

__device__ inline u16 f2bf(float f) {            // round-to-nearest-even fp32->bf16
  unsigned u = __float_as_uint(f);
  u = u + 0x7fffu + ((u >> 16) & 1u);
  return (u16)(u >> 16);
}
__device__ inline float bf2f(u16 h) { return __uint_as_float(((unsigned)h) << 16); }

// async global->LDS, 16B per lane (wave-uniform LDS base + lane*16; linear layout)
__device__ inline void gl16(const u16* g, u16* l) {
  __builtin_amdgcn_global_load_lds(
      (const __attribute__((address_space(1))) unsigned int*)g,
      (__attribute__((address_space(3))) unsigned int*)l, 16, 0, 0);
}

#define VM0  asm volatile("s_waitcnt vmcnt(0)" ::: "memory")
#define LK0  asm volatile("s_waitcnt lgkmcnt(0)" ::: "memory")
#define SB0  __builtin_amdgcn_sched_barrier(0)

// ---- merged prep: blocks 0..95 = W_eff transpose+split; 96.. = x hi/lo split ----
__global__ __launch_bounds__(256)
void prep_all(const float* __restrict__ x,
              const float* __restrict__ Wq, const float* __restrict__ Wk,
              const float* __restrict__ Wv,
              u16* __restrict__ WTh, u16* __restrict__ WTl,
              u16* __restrict__ xh, u16* __restrict__ xl) {
  if (blockIdx.x < 96) {
    __shared__ float sm[128][17];
    int t  = blockIdx.x >> 5;
    int nb = blockIdx.x & 31;
    const float* W = (t == 0) ? Wq : (t == 1) ? Wk : Wv;
    int n0 = nb << 4;
    int nl = threadIdx.x & 15;
    int kq = threadIdx.x >> 4;
    float s[8];
#pragma unroll
    for (int i = 0; i < 8; ++i) s[i] = 0.f;
#pragma unroll
    for (int h = 0; h < 8; ++h)
#pragma unroll
      for (int i = 0; i < 8; ++i)
        s[i] += W[(h * 128 + kq + (i << 4)) * 512 + n0 + nl];
#pragma unroll
    for (int i = 0; i < 8; ++i) sm[kq + (i << 4)][nl] = s[i];
    __syncthreads();
    int no = threadIdx.x >> 4;
    int k8 = (threadIdx.x & 15) << 3;
    bf16x8 h8, l8;
#pragma unroll
    for (int c = 0; c < 8; ++c) {
      float v = sm[k8 + c][no];
      u16 h = f2bf(v);
      h8[c] = (short)h;
      l8[c] = (short)f2bf(v - bf2f(h));
    }
    long o = (long)t * 65536 + (long)(n0 + no) * 128 + k8;
    *(bf16x8*)&WTh[o] = h8;
    *(bf16x8*)&WTl[o] = l8;
  } else {
    int i = (blockIdx.x - 96) * 256 + threadIdx.x;
    const f32x4* xx = (const f32x4*)x;
    f32x4 a = xx[i * 2], b = xx[i * 2 + 1];
    float v[8] = {a[0], a[1], a[2], a[3], b[0], b[1], b[2], b[3]};
    bf16x8 h8, l8;
#pragma unroll
    for (int j = 0; j < 8; ++j) {
      u16 h = f2bf(v[j]);
      h8[j] = (short)h;
      l8[j] = (short)f2bf(v[j] - bf2f(h));
    }
    ((bf16x8*)xh)[i] = h8;
    ((bf16x8*)xl)[i] = l8;
  }
}

// ---- fused Q/K/V projection: 3-pass split-bf16, coalesced bf16 epilogue ----
__global__ __launch_bounds__(256, 2)
void proj_fused(const u16* __restrict__ xh, const u16* __restrict__ xl,
                const u16* __restrict__ WTh, const u16* __restrict__ WTl,
                u16* __restrict__ Qh, u16* __restrict__ Kh, u16* __restrict__ Vh,
                const float* __restrict__ bq, const float* __restrict__ bk,
                const float* __restrict__ bv) {
  __shared__ __align__(16) char ldsraw[65536];
  u16* st = (u16*)ldsraw;

  int tid = threadIdx.x;
  int bid = blockIdx.x;
  bid = (bid & 7) * 192 + (bid >> 3);          // XCD swizzle (1536 = 8×192)
  int which = bid % 3;
  int tile  = bid / 3;
  int mt = tile >> 2;
  int nt = tile & 3;

  const u16* Ah = xh + (long)mt * (128 * 128);
  const u16* Al = xl + (long)mt * (128 * 128);
  const u16* Bh = WTh + which * 65536 + nt * 16384;
  const u16* Bl = WTl + which * 65536 + nt * 16384;
  const float* bias = (which == 0) ? bq : (which == 1) ? bk : bv;
  u16* C = (which == 0) ? Qh : (which == 1) ? Kh : Vh;

  int lane = tid & 63;
  int wv = tid >> 6;
  int wm = (wv >> 1) << 6;
  int wn = (wv & 1) << 6;
  int frow = lane & 15;
  int fk = (lane >> 4) << 3;

  f32x4 acc[4][4];
#pragma unroll
  for (int i = 0; i < 4; ++i)
#pragma unroll
    for (int j = 0; j < 4; ++j) {
      f32x4 z = {0.f, 0.f, 0.f, 0.f};
      acc[i][j] = z;
    }

  for (int kk = 0; kk < 2; ++kk) {
    int k0 = kk << 6;
#pragma unroll
    for (int j = 0; j < 4; ++j) {
      int c = j * 256 + tid;
      int row = c >> 3;
      int scol = ((c & 7) ^ (row & 7)) << 3;
      int ga = row * 128 + k0 + scol;
      int lo = c << 3;
      gl16(Ah + ga, st + lo);
      gl16(Al + ga, st + 8192 + lo);
      gl16(Bh + ga, st + 16384 + lo);
      gl16(Bl + ga, st + 24576 + lo);
    }
    __syncthreads();
#pragma unroll
    for (int ks = 0; ks < 2; ++ks) {
      int kb = (ks << 5) + fk;
      bf16x8 a_h[4], a_l[4], b_h[4], b_l[4];
#pragma unroll
      for (int i = 0; i < 4; ++i) {
        int ar = wm + (i << 4) + frow;
        int ao = ar * 64 + (kb ^ ((ar & 7) << 3));
        a_h[i] = *(const bf16x8*)&st[ao];
        a_l[i] = *(const bf16x8*)&st[8192 + ao];
        int br = wn + (i << 4) + frow;
        int bo = br * 64 + (kb ^ ((br & 7) << 3));
        b_h[i] = *(const bf16x8*)&st[16384 + bo];
        b_l[i] = *(const bf16x8*)&st[24576 + bo];
      }
#pragma unroll
      for (int i = 0; i < 4; ++i)
#pragma unroll
        for (int j = 0; j < 4; ++j) {
          acc[i][j] = __builtin_amdgcn_mfma_f32_16x16x32_bf16(a_h[i], b_h[j], acc[i][j], 0, 0, 0);
          acc[i][j] = __builtin_amdgcn_mfma_f32_16x16x32_bf16(a_l[i], b_h[j], acc[i][j], 0, 0, 0);
          acc[i][j] = __builtin_amdgcn_mfma_f32_16x16x32_bf16(a_h[i], b_l[j], acc[i][j], 0, 0, 0);
        }
    }
    __syncthreads();
  }

  // Coalesced epilogue via per-wave fp32 LDS transpose (intra-wave, no barrier)
  float* tr = ((float*)ldsraw) + wv * 2112;
  int lr = lane >> 3;
  int c8 = (lane & 7) << 3;
  int colbase = (nt << 7) + wn + c8;
  float bb[8];
#pragma unroll
  for (int c = 0; c < 8; ++c) bb[c] = bias[colbase + c];
  long rowg0 = (long)(mt << 7) + wm;
#pragma unroll
  for (int q = 0; q < 2; ++q) {
#pragma unroll
    for (int il = 0; il < 2; ++il) {
      int i = (q << 1) + il;
#pragma unroll
      for (int j = 0; j < 4; ++j)
#pragma unroll
        for (int r = 0; r < 4; ++r)
          tr[((il << 4) + ((lane >> 4) << 2) + r) * 66 + (j << 4) + (lane & 15)] =
              acc[i][j][r];
    }
#pragma unroll
    for (int p = 0; p < 4; ++p) {
      int rr = (p << 3) + lr;
      float v[8];
      *(f32x2*)&v[0] = *(const f32x2*)&tr[rr * 66 + c8];
      *(f32x2*)&v[2] = *(const f32x2*)&tr[rr * 66 + c8 + 2];
      *(f32x2*)&v[4] = *(const f32x2*)&tr[rr * 66 + c8 + 4];
      *(f32x2*)&v[6] = *(const f32x2*)&tr[rr * 66 + c8 + 6];
      bf16x8 o8;
#pragma unroll
      for (int c = 0; c < 8; ++c) o8[c] = (short)f2bf(v[c] + bb[c]);
      *(bf16x8*)&C[(rowg0 + (q << 5) + rr) * 512 + colbase] = o8;
    }
  }
}

// ---- fused attention v9 ----
// 256 blocks (32 batches × 8 jb of 64 q-rows), 512 threads, 1 blk/CU (100KB).
// Wave nw owns attn-cols/v-rows [nw*64,+64); private 4KB slice [64 tok][32 feat].
// 32x32x16 MFMA, wave tile 64 cols × 64 q (2×2 tiles, acc f32x16).
// C/D layout (m74/m101): col=lane&31, row=(reg&3)+8*(reg>>2)+4*(lane>>5).
// LDS: QP[0,64K) Q [64q][512f] (ph1) aliased by P [64q][512] bf16 (ph2);
// B[64K,96K) 8 × 4KB slices; smax/ssum at 96K.
__global__ __launch_bounds__(512, 2)
void attn_fused(const u16* __restrict__ Q, const u16* __restrict__ K,
                const u16* __restrict__ V, float* __restrict__ OUT) {
  __shared__ __align__(16) char LDS[102400];
  u16* QP = (u16*)LDS;                   // 64KB Q (ph1) / P (ph2)
  u16* B  = (u16*)(LDS + 65536);         // 32KB: 8 wave-private 4KB slices
  float* smax = (float*)(LDS + 98304);   // [64][8]
  float* ssum = (float*)(LDS + 100352);  // [64][8]

  int tid = threadIdx.x;
  int p = blockIdx.x;
  int xcd = p & 7, idx = p >> 3;
  int b  = (xcd << 2) + (idx >> 3);      // 4 batches per XCD
  int jb = idx & 7;

  const u16* Qp = Q + ((long)b * 512 + jb * 64) * 512;
  const u16* Kp = K + (long)b * 262144;
  const u16* Vp = V + (long)b * 262144;

  int lane = tid & 63, nw = tid >> 6;
  int l31 = lane & 31, l5 = lane >> 5;
  u16* myB = B + (nw << 11);             // 2048 u16 = 4KB private slice
  int tokbase = nw << 6;                 // wave's 64 tokens / attn-cols / v-rows

  // wave-private stage: [64 tok][32 feat] at feat k0 (4 gl16; 64B rows)
  auto stageW = [&](const u16* src, int k0) {
#pragma unroll
    for (int j = 0; j < 4; ++j) {
      int u = (j << 6) + lane;
      int tok = u >> 2, sl = u & 3;
      int ps = (sl ^ (tok & 3) ^ ((tok >> 2) & 3)) & 3;   // inverse slot swizzle
      gl16(src + (long)(tokbase + tok) * 512 + k0 + (ps << 3), myB + (u << 3));
    }
  };
  // A-frag (32x32x16): col-tile c, k-slice ks: row=tok=c*32+l31, k=(ks*16)+(l5*8)
  auto rA = [&](int c, int ks) -> bf16x8 {
    int tok = (c << 5) + l31;
    int sl = (ks << 1) + l5;
    int ps = (sl ^ (tok & 3) ^ ((tok >> 2) & 3)) & 3;
    return *(const bf16x8*)&myB[(tok << 5) + (ps << 3)];
  };
  // B-frag from QP region (Q in ph1, P in ph2): row q, 16B-slot sl (0..63)
  auto rQ = [&](int q, int sl) -> bf16x8 {
    return *(const bf16x8*)&QP[(q << 9) + ((sl ^ (q & 7)) << 3)];
  };

  // prologue: stage Q (64KB, 8 gl16/thread) + own K step-0; one full drain
#pragma unroll
  for (int j = 0; j < 8; ++j) {
    int u = (j << 9) + tid;
    int row = u >> 6, sl = u & 63;
    gl16(Qp + (long)row * 512 + ((sl ^ (row & 7)) << 3), QP + (u << 3));
  }
  stageW(Kp, 0);
  __syncthreads();                       // drains vmcnt; Q + K0 visible

  // ---------------- phase 1: S^T = K·Q^T, barrier-free ----------------
  // acc[c][j]: 32x32 tile, rows = attn-cols nw*64+c*32+rowfn, cols = q j*32+l31
  f32x16 acc[2][2];
#pragma unroll
  for (int c = 0; c < 2; ++c)
#pragma unroll
    for (int j = 0; j < 2; ++j)
#pragma unroll
      for (int r = 0; r < 16; ++r) acc[c][j][r] = 0.f;

  for (int s = 0; s < 16; ++s) {
    if (s) VM0;                          // own 4 stage loads complete
    bf16x8 af[2][2], qf[2][2];
#pragma unroll
    for (int ks = 0; ks < 2; ++ks) {
#pragma unroll
      for (int c = 0; c < 2; ++c) af[ks][c] = rA(c, ks);
#pragma unroll
      for (int j = 0; j < 2; ++j)
        qf[ks][j] = rQ((j << 5) + l31, (s << 2) + (ks << 1) + l5);
    }
    LK0; SB0;                            // frag reads done; slice reusable
    if (s < 15) stageW(Kp, (s + 1) << 5);
    else        stageW(Vp, 0);           // prefetch own V step-0 under softmax
    __builtin_amdgcn_s_setprio(1);
#pragma unroll
    for (int ks = 0; ks < 2; ++ks)
#pragma unroll
      for (int c = 0; c < 2; ++c)
#pragma unroll
        for (int j = 0; j < 2; ++j)
          acc[c][j] = __builtin_amdgcn_mfma_f32_32x32x16_bf16(
              af[ks][c], qf[ks][j], acc[c][j], 0, 0, 0);
    __builtin_amdgcn_s_setprio(0);
  }

  // ---------------- softmax per q over 512 attn-cols ----------------
  // lane's q values: q = j*32 + l31 (j=0,1); 32 vals per q: acc[c][j][0..15]
  float mx[2], sm[2], inv_[2];
#pragma unroll
  for (int j = 0; j < 2; ++j) {
    float m = acc[0][j][0];
#pragma unroll
    for (int c = 0; c < 2; ++c)
#pragma unroll
      for (int r = 0; r < 16; ++r) m = fmaxf(m, acc[c][j][r]);
    m = fmaxf(m, __shfl_xor(m, 32));     // merge row-halves (same q at l^32)
    mx[j] = m;
  }
  if (l5 == 0) {
#pragma unroll
    for (int j = 0; j < 2; ++j) smax[(((j << 5) + l31) << 3) + nw] = mx[j];
  }
  __syncthreads();
#pragma unroll
  for (int j = 0; j < 2; ++j) {
    f32x4 a = *(const f32x4*)&smax[((j << 5) + l31) << 3];
    f32x4 c = *(const f32x4*)&smax[((((j << 5) + l31) << 3) + 4)];
    mx[j] = fmaxf(fmaxf(fmaxf(a[0], a[1]), fmaxf(a[2], a[3])),
                  fmaxf(fmaxf(c[0], c[1]), fmaxf(c[2], c[3])));
    sm[j] = 0.f;
  }
#pragma unroll
  for (int c = 0; c < 2; ++c)
#pragma unroll
    for (int j = 0; j < 2; ++j)
#pragma unroll
      for (int r = 0; r < 16; ++r) {
        float pv = __expf((acc[c][j][r] - mx[j]) * 0.125f);   // fold /8 scale
        acc[c][j][r] = pv;
        sm[j] += pv;
      }
#pragma unroll
  for (int j = 0; j < 2; ++j) sm[j] += __shfl_xor(sm[j], 32);
  if (l5 == 0) {
#pragma unroll
    for (int j = 0; j < 2; ++j) ssum[(((j << 5) + l31) << 3) + nw] = sm[j];
  }
  __syncthreads();
#pragma unroll
  for (int j = 0; j < 2; ++j) {
    f32x4 a = *(const f32x4*)&ssum[((j << 5) + l31) << 3];
    f32x4 c = *(const f32x4*)&ssum[((((j << 5) + l31) << 3) + 4)];
    inv_[j] = 1.f / (a[0] + a[1] + a[2] + a[3] + c[0] + c[1] + c[2] + c[3]);
  }
  // write P [64 q][512 keys] over Q region; rows of reg-group g: cols 8g+4*l5+0..3
#pragma unroll
  for (int j = 0; j < 2; ++j) {
    int q = (j << 5) + l31;
    int rowoff = q << 10;
    int swz = (q & 7) << 4;
#pragma unroll
    for (int c = 0; c < 2; ++c)
#pragma unroll
      for (int g = 0; g < 4; ++g) {
        int col = (nw << 6) + (c << 5) + (g << 3) + (l5 << 2);
        unsigned lo = (unsigned)f2bf(acc[c][j][(g << 2) + 0] * inv_[j]) |
                      ((unsigned)f2bf(acc[c][j][(g << 2) + 1] * inv_[j]) << 16);
        unsigned hi = (unsigned)f2bf(acc[c][j][(g << 2) + 2] * inv_[j]) |
                      ((unsigned)f2bf(acc[c][j][(g << 2) + 3] * inv_[j]) << 16);
        u32x2 w = {lo, hi};
        *(u32x2*)(LDS + ((rowoff + (col << 1)) ^ swz)) = w;
      }
  }
  __syncthreads();                       // P visible; own V step-0 staged (drained)

  // ---------------- phase 2: OUT = V·P^T, barrier-free (reuse acc) ----------------
#pragma unroll
  for (int c = 0; c < 2; ++c)
#pragma unroll
    for (int j = 0; j < 2; ++j)
#pragma unroll
      for (int r = 0; r < 16; ++r) acc[c][j][r] = 0.f;

  for (int s = 0; s < 16; ++s) {
    if (s) VM0;
    bf16x8 vf[2][2], pf[2][2];
#pragma unroll
    for (int ks = 0; ks < 2; ++ks) {
#pragma unroll
      for (int c = 0; c < 2; ++c) vf[ks][c] = rA(c, ks);
#pragma unroll
      for (int j = 0; j < 2; ++j)
        pf[ks][j] = rQ((j << 5) + l31, (s << 2) + (ks << 1) + l5);
    }
    LK0; SB0;
    if (s < 15) stageW(Vp, (s + 1) << 5);
    __builtin_amdgcn_s_setprio(1);
#pragma unroll
    for (int ks = 0; ks < 2; ++ks)
#pragma unroll
      for (int c = 0; c < 2; ++c)
#pragma unroll
        for (int j = 0; j < 2; ++j)
          acc[c][j] = __builtin_amdgcn_mfma_f32_32x32x16_bf16(
              vf[ks][c], pf[ks][j], acc[c][j], 0, 0, 0);
    __builtin_amdgcn_s_setprio(0);
  }

  // epilogue: OUT[b, vtok, jb*64 + q]; lanes 0-31 = consecutive q -> 128B stores
  float* Ob = OUT + (long)b * 262144 + jb * 64;
#pragma unroll
  for (int c = 0; c < 2; ++c)
#pragma unroll
    for (int j = 0; j < 2; ++j)
#pragma unroll
      for (int r = 0; r < 16; ++r) {
        int vtok = (nw << 6) + (c << 5) + (r & 3) + ((r >> 2) << 3) + (l5 << 2);
        Ob[(long)vtok * 512 + (j << 5) + l31] = acc[c][j][r];
      }
}

extern "C" void kernel_launch(void* const* d_in, const int* in_sizes, int n_in,
                              void* d_out, int out_size, void* d_ws, size_t ws_size,
                              hipStream_t stream) {
  const float* x  = (const float*)d_in[0];
  const float* Wq = (const float*)d_in[1];
  const float* bq = (const float*)d_in[2];
  const float* Wk = (const float*)d_in[3];
  const float* bk = (const float*)d_in[4];
  const float* Wv = (const float*)d_in[5];
  const float* bv = (const float*)d_in[6];
  float* out = (float*)d_out;

  char* ws = (char*)d_ws;
  size_t off = 0;
  auto alloc = [&](size_t bytes) -> char* {
    char* p = ws + off;
    off = (off + bytes + 255) & ~(size_t)255;
    return p;
  };
  u16* WTh = (u16*)alloc((size_t)3 * 512 * 128 * 2);
  u16* WTl = (u16*)alloc((size_t)3 * 512 * 128 * 2);
  u16* xh  = (u16*)alloc((size_t)16384 * 128 * 2);
  u16* xl  = (u16*)alloc((size_t)16384 * 128 * 2);
  u16* Qh  = (u16*)alloc((size_t)16384 * 512 * 2);
  u16* Kh  = (u16*)alloc((size_t)16384 * 512 * 2);
  u16* Vh  = (u16*)alloc((size_t)16384 * 512 * 2);

  prep_all<<<1120, 256, 0, stream>>>(x, Wq, Wk, Wv, WTh, WTl, xh, xl);
  proj_fused<<<1536, 256, 0, stream>>>(xh, xl, WTh, WTl, Qh, Kh, Vh, bq, bk, bv);
  attn_fused<<<256, 512, 0, stream>>>(Qh, Kh, Vh, out);
}